// Round 2
// baseline (391.120 us; speedup 1.0000x reference)
//
#include <hip/hip_runtime.h>

#define ROW_LEN 128
#define VOCAB_WORDS 1000   // ceil(32000/32)

__global__ __launch_bounds__(256) void symfeat_kernel(
    const int* __restrict__ ids, const int* __restrict__ amask,
    const float* __restrict__ W1, const float* __restrict__ b1,
    const float* __restrict__ W2, const float* __restrict__ b2,
    float* __restrict__ out, int B)
{
    // LDS: 4 per-wave vocab bitmaps + staged MLP params
    __shared__ unsigned bm[4][VOCAB_WORDS];
    __shared__ float W1s[96];
    __shared__ float b1s[32];
    __shared__ float W2s[1024];
    __shared__ float b2s[32];

    const int t = threadIdx.x;

    // zero all 4 bitmaps (4000 dwords) + stage params; one barrier
    unsigned* bmflat = (unsigned*)bm;
    #pragma unroll
    for (int i = 0; i < 15; ++i) bmflat[t + i * 256] = 0u;
    if (t < 4000 - 15 * 256) bmflat[t + 15 * 256] = 0u;
    for (int i = t; i < 1024; i += 256) W2s[i] = W2[i];
    if (t < 96) W1s[t] = W1[t];
    if (t < 32) { b1s[t] = b1[t]; b2s[t] = b2[t]; }
    __syncthreads();

    const int wave = t >> 6;   // 0..3
    const int lane = t & 63;
    const int row  = blockIdx.x * 4 + wave;
    if (row >= B) return;      // B divisible by 4; cosmetic guard

    unsigned* mybm = bm[wave];

    // coalesced loads: lane i takes positions 2i, 2i+1 of this row
    const long vbase = (long)row * (ROW_LEN / 2) + lane; // int2 units
    const int2 id2 = ((const int2*)ids)[vbase];
    const int2 mk2 = ((const int2*)amask)[vbase];

    int cnt = 0;   // new-bit (unique) contributions
    int sl  = 0;   // mask sum contribution

    // two independent atomicOr inserts — no retry loop, no divergence
    if (mk2.x != 0) {
        sl++;
        const unsigned tok = (unsigned)id2.x;
        const unsigned m = 1u << (tok & 31u);
        const unsigned old = atomicOr(&mybm[tok >> 5], m);
        cnt += ((old & m) == 0u);
    }
    if (mk2.y != 0) {
        sl++;
        const unsigned tok = (unsigned)id2.y;
        const unsigned m = 1u << (tok & 31u);
        const unsigned old = atomicOr(&mybm[tok >> 5], m);
        cnt += ((old & m) == 0u);
    }

    // packed wave-64 reduction: low 16 bits = seq_len, high 16 = uniq
    unsigned packed = (unsigned)sl | ((unsigned)cnt << 16);
    #pragma unroll
    for (int off = 32; off > 0; off >>= 1)
        packed += __shfl_down(packed, off, 64);
    packed = __shfl(packed, 0, 64);  // broadcast

    const int seq  = (int)(packed & 0xFFFFu);
    const int uniq = (int)(packed >> 16);

    const float f0 = (float)seq  * (1.0f / 128.0f);
    const float f1 = (float)uniq * (1.0f / 128.0f);
    const float f2 = (seq > 0) ? ((float)uniq / (float)seq) : 0.0f;

    // layer 1: lane j (and j+32, redundantly) computes h[j]
    const int j = lane & 31;
    float hv = b1s[j];
    hv = fmaf(f0, W1s[j],      hv);
    hv = fmaf(f1, W1s[32 + j], hv);
    hv = fmaf(f2, W1s[64 + j], hv);
    hv = fmaxf(hv, 0.0f);

    // layer 2: lane k accumulates over all 32 h via uniform-index shuffle
    float acc = b2s[j];
    #pragma unroll
    for (int jj = 0; jj < 32; ++jj) {
        const float hj = __shfl(hv, jj, 64);
        acc = fmaf(hj, W2s[jj * 32 + j], acc);
    }
    acc = fmaxf(acc, 0.0f);

    if (lane < 32) out[(long)row * 32 + j] = acc;
}

extern "C" void kernel_launch(void* const* d_in, const int* in_sizes, int n_in,
                              void* d_out, int out_size, void* d_ws, size_t ws_size,
                              hipStream_t stream) {
    const int*   ids   = (const int*)d_in[0];
    const int*   amask = (const int*)d_in[1];
    const float* W1    = (const float*)d_in[2];
    const float* b1    = (const float*)d_in[3];
    const float* W2    = (const float*)d_in[4];
    const float* b2    = (const float*)d_in[5];
    float* out = (float*)d_out;

    const int B = in_sizes[0] / ROW_LEN;          // 262144
    const int blocks = (B + 3) / 4;               // 4 rows (one per wave) per block

    symfeat_kernel<<<blocks, 256, 0, stream>>>(ids, amask, W1, b1, W2, b2, out, B);
}

// Round 3
// 292.148 us; speedup vs baseline: 1.3388x; 1.3388x over previous
//
#include <hip/hip_runtime.h>

#define ROW_LEN 128
#define NPAIR (129 * 129)   // (seq, uniq) pairs, each in [0,128]

// Kernel A: precompute MLP(feats(seq,uniq)) for all 16641 pairs -> table[p][32].
// Tiny (2081 blocks); params L2-resident; rebuilt every call (ws is re-poisoned).
__global__ __launch_bounds__(256) void mlp_table_kernel(
    const float* __restrict__ W1, const float* __restrict__ b1,
    const float* __restrict__ W2, const float* __restrict__ b2,
    float* __restrict__ table)
{
    const int tid = blockIdx.x * 256 + threadIdx.x;
    if (tid >= NPAIR * 32) return;
    const int p = tid >> 5;
    const int j = tid & 31;
    const int seq  = p / 129;
    const int uniq = p % 129;
    const float f0 = (float)seq  * (1.0f / 128.0f);
    const float f1 = (float)uniq * (1.0f / 128.0f);
    const float f2 = (seq > 0) ? ((float)uniq / (float)seq) : 0.0f;

    float acc = b2[j];
    #pragma unroll
    for (int jj = 0; jj < 32; ++jj) {
        float h = b1[jj];                 // lane-uniform -> scalar loads
        h = fmaf(f0, W1[jj],      h);
        h = fmaf(f1, W1[32 + jj], h);
        h = fmaf(f2, W1[64 + jj], h);
        h = fmaxf(h, 0.0f);
        acc = fmaf(h, W2[jj * 32 + j], acc);
    }
    table[tid] = fmaxf(acc, 0.0f);
}

// Kernel B: one wave per row. Bitmap unique-count (wave-local, barrier-free),
// butterfly reduce, then 128B table gather as the entire epilogue.
__global__ __launch_bounds__(256) void rows_kernel(
    const int* __restrict__ ids, const int* __restrict__ amask,
    const float* __restrict__ table, float* __restrict__ out, int B)
{
    __shared__ unsigned bm[4][1024];   // 4 KB bitmap per wave (32000 bits used)

    const int wave = threadIdx.x >> 6;
    const int lane = threadIdx.x & 63;
    const int row  = blockIdx.x * 4 + wave;
    if (row >= B) return;              // B divisible by 4; cosmetic

    // wave-local zero: 256 uint4 per bitmap, 4 ds_write_b128 per lane.
    // Same-wave DS ops are ordered -> no barrier needed anywhere.
    uint4* mybm4 = (uint4*)bm[wave];
    #pragma unroll
    for (int i = 0; i < 4; ++i) mybm4[lane + i * 64] = make_uint4(0u, 0u, 0u, 0u);

    // coalesced loads: lane i takes positions 2i, 2i+1 of this row
    const long vbase = (long)row * (ROW_LEN / 2) + lane;  // int2 units
    const int2 id2 = ((const int2*)ids)[vbase];
    const int2 mk2 = ((const int2*)amask)[vbase];

    unsigned* mybm = bm[wave];
    int sl = 0, cnt = 0;
    if (mk2.x != 0) {
        sl++;
        const unsigned tok = (unsigned)id2.x;
        const unsigned m = 1u << (tok & 31u);
        const unsigned old = atomicOr(&mybm[tok >> 5], m);
        cnt += ((old & m) == 0u);
    }
    if (mk2.y != 0) {
        sl++;
        const unsigned tok = (unsigned)id2.y;
        const unsigned m = 1u << (tok & 31u);
        const unsigned old = atomicOr(&mybm[tok >> 5], m);
        cnt += ((old & m) == 0u);
    }

    // butterfly reduction -> all lanes hold totals; low16=seq, high16=uniq
    unsigned packed = (unsigned)sl | ((unsigned)cnt << 16);
    #pragma unroll
    for (int off = 1; off < 64; off <<= 1)
        packed += __shfl_xor(packed, off, 64);

    const int seq  = (int)(packed & 0xFFFFu);
    const int uniq = (int)(packed >> 16);

    if (lane < 32) {
        const int p = seq * 129 + uniq;
        out[(long)row * 32 + lane] = table[p * 32 + lane];  // L2-hot 128B gather
    }
}

extern "C" void kernel_launch(void* const* d_in, const int* in_sizes, int n_in,
                              void* d_out, int out_size, void* d_ws, size_t ws_size,
                              hipStream_t stream) {
    const int*   ids   = (const int*)d_in[0];
    const int*   amask = (const int*)d_in[1];
    const float* W1    = (const float*)d_in[2];
    const float* b1    = (const float*)d_in[3];
    const float* W2    = (const float*)d_in[4];
    const float* b2    = (const float*)d_in[5];
    float* out   = (float*)d_out;
    float* table = (float*)d_ws;       // needs NPAIR*32*4 = 2.13 MB of ws

    const int B = in_sizes[0] / ROW_LEN;              // 262144

    const int tblThreads = NPAIR * 32;
    mlp_table_kernel<<<(tblThreads + 255) / 256, 256, 0, stream>>>(W1, b1, W2, b2, table);

    rows_kernel<<<(B + 3) / 4, 256, 0, stream>>>(ids, amask, table, out, B);
}

// Round 4
// 281.057 us; speedup vs baseline: 1.3916x; 1.0395x over previous
//
#include <hip/hip_runtime.h>

#define ROW_LEN 128
#define NPAIR (129 * 129)   // (seq, uniq) pairs, each in [0,128]

// Kernel A: precompute MLP(feats(seq,uniq)) for all 16641 pairs -> table[p][32].
__global__ __launch_bounds__(256) void mlp_table_kernel(
    const float* __restrict__ W1, const float* __restrict__ b1,
    const float* __restrict__ W2, const float* __restrict__ b2,
    float* __restrict__ table)
{
    const int tid = blockIdx.x * 256 + threadIdx.x;
    if (tid >= NPAIR * 32) return;
    const int p = tid >> 5;
    const int j = tid & 31;
    const int seq  = p / 129;
    const int uniq = p % 129;
    const float f0 = (float)seq  * (1.0f / 128.0f);
    const float f1 = (float)uniq * (1.0f / 128.0f);
    const float f2 = (seq > 0) ? ((float)uniq / (float)seq) : 0.0f;

    float acc = b2[j];
    #pragma unroll
    for (int jj = 0; jj < 32; ++jj) {
        float h = b1[jj];                 // lane-uniform -> scalar loads
        h = fmaf(f0, W1[jj],      h);
        h = fmaf(f1, W1[32 + jj], h);
        h = fmaf(f2, W1[64 + jj], h);
        h = fmaxf(h, 0.0f);
        acc = fmaf(h, W2[jj * 32 + j], acc);
    }
    table[tid] = fmaxf(acc, 0.0f);
}

// Kernel B: TWO rows per wave. Lanes 0..31 own row 2p, lanes 32..63 own row 2p+1.
// Each lane: int4 = 4 tokens. Bitmap insert via atomicOr; seq/uniq via
// ballot+popc (no DS shuffles). No __syncthreads (same-wave DS ops are ordered).
__global__ __launch_bounds__(256) void rows_kernel(
    const int* __restrict__ ids, const int* __restrict__ amask,
    const float* __restrict__ table, float* __restrict__ out, int B)
{
    __shared__ unsigned bm[8][1024];   // 2 bitmaps per wave (4 KB each), 32 KB total

    const int wave = threadIdx.x >> 6;
    const int lane = threadIdx.x & 63;
    const int half = lane >> 5;                       // which row of the pair
    const long pair = (long)blockIdx.x * 4 + wave;    // rows 2*pair, 2*pair+1
    if (pair * 2 >= B) return;                        // B % 8 == 0; cosmetic

    // issue global loads FIRST so the bitmap zeroing overlaps HBM latency.
    // Pair-chunk = 256 ints = 64 int4; lane i covers ints [4i,4i+4).
    const long v = pair * 64 + lane;
    const int4 id4 = ((const int4*)ids)[v];
    const int4 mk4 = ((const int4*)amask)[v];

    // zero this wave's two bitmaps: 512 uint4 / 64 lanes = 8 ds_write_b128
    uint4* z = (uint4*)bm[wave * 2];
    #pragma unroll
    for (int i = 0; i < 8; ++i) z[lane + i * 64] = make_uint4(0u, 0u, 0u, 0u);

    unsigned* mybm = bm[wave * 2 + half];

    int n0 = 0, n1 = 0, n2 = 0, n3 = 0;   // "new token" flags
    if (mk4.x != 0) {
        const unsigned t = (unsigned)id4.x, m = 1u << (t & 31u);
        n0 = ((atomicOr(&mybm[t >> 5], m) & m) == 0u);
    }
    if (mk4.y != 0) {
        const unsigned t = (unsigned)id4.y, m = 1u << (t & 31u);
        n1 = ((atomicOr(&mybm[t >> 5], m) & m) == 0u);
    }
    if (mk4.z != 0) {
        const unsigned t = (unsigned)id4.z, m = 1u << (t & 31u);
        n2 = ((atomicOr(&mybm[t >> 5], m) & m) == 0u);
    }
    if (mk4.w != 0) {
        const unsigned t = (unsigned)id4.w, m = 1u << (t & 31u);
        n3 = ((atomicOr(&mybm[t >> 5], m) & m) == 0u);
    }

    // wave totals via ballot; low 32 bits = row A lanes, high 32 = row B
    const unsigned long long s0 = __ballot(mk4.x != 0);
    const unsigned long long s1 = __ballot(mk4.y != 0);
    const unsigned long long s2 = __ballot(mk4.z != 0);
    const unsigned long long s3 = __ballot(mk4.w != 0);
    const unsigned long long u0 = __ballot(n0 != 0);
    const unsigned long long u1 = __ballot(n1 != 0);
    const unsigned long long u2 = __ballot(n2 != 0);
    const unsigned long long u3 = __ballot(n3 != 0);

    const int sh = lane & 32;   // 0 for row A lanes, 32 for row B lanes
    const int seq  = __popc((unsigned)(s0 >> sh)) + __popc((unsigned)(s1 >> sh))
                   + __popc((unsigned)(s2 >> sh)) + __popc((unsigned)(s3 >> sh));
    const int uniq = __popc((unsigned)(u0 >> sh)) + __popc((unsigned)(u1 >> sh))
                   + __popc((unsigned)(u2 >> sh)) + __popc((unsigned)(u3 >> sh));

    // epilogue: 128B L2-hot gather per row; contiguous 256B store per wave
    const int p = seq * 129 + uniq;
    out[pair * 64 + lane] = table[p * 32 + (lane & 31)];
}

extern "C" void kernel_launch(void* const* d_in, const int* in_sizes, int n_in,
                              void* d_out, int out_size, void* d_ws, size_t ws_size,
                              hipStream_t stream) {
    const int*   ids   = (const int*)d_in[0];
    const int*   amask = (const int*)d_in[1];
    const float* W1    = (const float*)d_in[2];
    const float* b1    = (const float*)d_in[3];
    const float* W2    = (const float*)d_in[4];
    const float* b2    = (const float*)d_in[5];
    float* out   = (float*)d_out;
    float* table = (float*)d_ws;       // NPAIR*32*4 = 2.13 MB of ws

    const int B = in_sizes[0] / ROW_LEN;              // 262144

    const int tblThreads = NPAIR * 32;
    mlp_table_kernel<<<(tblThreads + 255) / 256, 256, 0, stream>>>(W1, b1, W2, b2, table);

    // 2 rows per wave, 4 waves per block -> 8 rows per block
    rows_kernel<<<(B + 7) / 8, 256, 0, stream>>>(ids, amask, table, out, B);
}